// Round 4
// baseline (548.168 us; speedup 1.0000x reference)
//
#include <hip/hip_runtime.h>
#include <stdint.h>

// WARP loss, B=1024, Y=50000. inputs: input_ f32[B*Y], target f32[B*Y],
// max_num_trials i32[1]; output f32[1] = sum of per-row losses.
//
// Exact-RNG reduction (absmax 0.0 R1-R3): first violator in the random
// permutation == violator with min (u_bits>>9, col); num_trials-1 == rank ==
// #{cols != pos with key < kstar}. Keys are input-independent -> gen kernel
// pushes all keys < T=2^13 into per-(row,seg) candidate slots (LDS-counted,
// no global init needed); resolve does margin tests on candidates only; rare
// rows (overflow / no violating candidate) take an exact full-scan fallback.
// R4: 4 interleaved threefry chains per thread (kills the serial dep-chain
// stall seen in R3: VALUBusy 74% @ 163us), LDS candidate counter, no memset.
#define BN 1024
#define YN 50000
#define SEGS 8
#define SEGLEN 6250          // YN / SEGS
#define SEGCAP 32            // Poisson(6.1)/seg, P(>32) ~ 1e-10
#define KEYHI_T (1u << 13)   // threshold on (bits>>9)

// ---------------- Threefry-2x32, key (0,42), counter (0, i), 4-wide ---------
#define ROTL(x, r) __builtin_amdgcn_alignbit((x), (x), 32u - (r))
#define TF4(r) { \
    x0[0] += x1[0]; x0[1] += x1[1]; x0[2] += x1[2]; x0[3] += x1[3]; \
    x1[0] = ROTL(x1[0], r); x1[1] = ROTL(x1[1], r); \
    x1[2] = ROTL(x1[2], r); x1[3] = ROTL(x1[3], r); \
    x1[0] ^= x0[0]; x1[1] ^= x0[1]; x1[2] ^= x0[2]; x1[3] ^= x0[3]; }
#define INJ4(a, b) { \
    x0[0] += (a); x0[1] += (a); x0[2] += (a); x0[3] += (a); \
    x1[0] += (b); x1[1] += (b); x1[2] += (b); x1[3] += (b); }

__device__ __forceinline__ void tf_bits4(uint32_t ctr0, uint32_t out[4]) {
    const uint32_t ks0 = 0u, ks1 = 42u, ks2 = 0x1BD11BDAu ^ 0u ^ 42u;
    uint32_t x0[4], x1[4];
#pragma unroll
    for (int k = 0; k < 4; ++k) { x0[k] = ks0; x1[k] = ctr0 + (uint32_t)k + ks1; }
    TF4(13) TF4(15) TF4(26) TF4(6)
    INJ4(ks1, ks2 + 1u)
    TF4(17) TF4(29) TF4(16) TF4(24)
    INJ4(ks2, ks0 + 2u)
    TF4(13) TF4(15) TF4(26) TF4(6)
    INJ4(ks0, ks1 + 3u)
    TF4(17) TF4(29) TF4(16) TF4(24)
    INJ4(ks1, ks2 + 4u)
    TF4(13) TF4(15) TF4(26) TF4(6)
    INJ4(ks2, ks0 + 5u)
#pragma unroll
    for (int k = 0; k < 4; ++k) out[k] = x0[k] ^ x1[k];
}

// single-counter variant for the fallback kernel (rare rows)
__device__ __forceinline__ uint32_t tf_bits(uint32_t ctr) {
    const uint32_t ks0 = 0u, ks1 = 42u, ks2 = 0x1BD11BDAu ^ 0u ^ 42u;
    uint32_t x0 = ks0, x1 = ctr + ks1;
#define TFR(r) { x0 += x1; x1 = ROTL(x1, r); x1 ^= x0; }
    TFR(13) TFR(15) TFR(26) TFR(6)
    x0 += ks1; x1 += ks2 + 1u;
    TFR(17) TFR(29) TFR(16) TFR(24)
    x0 += ks2; x1 += ks0 + 2u;
    TFR(13) TFR(15) TFR(26) TFR(6)
    x0 += ks0; x1 += ks1 + 3u;
    TFR(17) TFR(29) TFR(16) TFR(24)
    x0 += ks1; x1 += ks2 + 4u;
    TFR(13) TFR(15) TFR(26) TFR(6)
    x0 += ks2; x1 += ks0 + 5u;
    return x0 ^ x1;
}

// ws layout (4B units):
//   cnt_seg[BN*SEGS] @0 | pos[BN] @8BN | ps[BN] @9BN | row_loss[BN] @10BN |
//   flag[BN] @11BN | cand[BN*SEGS*SEGCAP] @12BN          (total ~1.06 MB)
struct WS {
    uint32_t* cnt_seg; int* pos; float* ps; float* row_loss; int* flag; uint32_t* cand;
};
static inline WS ws_layout(void* d_ws) {
    uint32_t* p = (uint32_t*)d_ws;
    WS w;
    w.cnt_seg = p;
    w.pos = (int*)(p + SEGS * BN);
    w.ps = (float*)(p + (SEGS + 1) * BN);
    w.row_loss = (float*)(p + (SEGS + 2) * BN);
    w.flag = (int*)(p + (SEGS + 3) * BN);
    w.cand = p + (SEGS + 4) * BN;
    return w;
}

// ---------------- Kernel 1: candidate gen (threefry) + target scan ----------
// blocks [0, BN): target scan (memory-bound, hides under the threefry blocks).
// blocks [BN, BN + BN*SEGS): threefry over one (row, seg).
__global__ __launch_bounds__(256) void gen_kernel(
    const float* __restrict__ input, const float* __restrict__ target,
    uint32_t* __restrict__ cnt_seg, uint32_t* __restrict__ cand,
    int* __restrict__ pos_out, float* __restrict__ ps_out)
{
    const int tid = threadIdx.x;
    if (blockIdx.x < BN) {
        const int row = blockIdx.x;
        const size_t base = (size_t)row * YN;
        __shared__ volatile int s_pos;
        if (tid == 0) s_pos = -1;
        __syncthreads();
        const float4* t4 = (const float4*)(target + base);
        for (int j4 = tid; j4 < YN / 4; j4 += 256) {
            if (s_pos >= 0) break;               // benign racy early-exit
            float4 v = t4[j4];
            int c0 = 4 * j4;
            if (v.x != 0.0f) s_pos = c0;
            if (v.y != 0.0f) s_pos = c0 + 1;
            if (v.z != 0.0f) s_pos = c0 + 2;
            if (v.w != 0.0f) s_pos = c0 + 3;
        }
        __syncthreads();
        if (tid == 0) {
            int p = s_pos;
            pos_out[row] = p;
            ps_out[row] = input[base + p];
        }
        return;
    }
    const int b = blockIdx.x - BN;
    const int row = b >> 3;                      // b / SEGS
    const int seg = b & 7;
    const uint32_t rowbase = (uint32_t)row * (uint32_t)YN;
    const int start = seg * SEGLEN;
    const int end = start + SEGLEN;
    __shared__ uint32_t lcnt;
    if (tid == 0) lcnt = 0;
    __syncthreads();
    uint32_t* mycand = cand + (size_t)(row * SEGS + seg) * SEGCAP;
    for (int col0 = start + tid * 4; col0 < end; col0 += 1024) {
        uint32_t o[4];
        tf_bits4(rowbase + (uint32_t)col0, o);
#pragma unroll
        for (int k = 0; k < 4; ++k) {
            uint32_t kh = o[k] >> 9;
            int col = col0 + k;
            if (kh < KEYHI_T && col < end) {     // tail hashes never pushed
                uint32_t idx = atomicAdd(&lcnt, 1u);
                if (idx < SEGCAP) mycand[idx] = (kh << 17) | (uint32_t)col;
            }
        }
    }
    __syncthreads();
    if (tid == 0) cnt_seg[row * SEGS + seg] = lcnt;
}

// ---------------- Kernel 2: resolve per row from candidate lists ------------
// one wave per row; always writes flag[row] (0 fast-path done, 1 fallback).
__global__ __launch_bounds__(256) void resolve_kernel(
    const float* __restrict__ input, const uint32_t* __restrict__ cnt_seg,
    const uint32_t* __restrict__ cand, const int* __restrict__ pos_,
    const float* __restrict__ ps_, const int* __restrict__ mt_ptr,
    float* __restrict__ row_loss, int* __restrict__ flag)
{
    const int gtid = blockIdx.x * 256 + threadIdx.x;
    const int row = gtid >> 6;
    const int lane = gtid & 63;
    const uint32_t* cs = cnt_seg + row * SEGS;
    uint32_t csl[SEGS];
    bool over = false;
#pragma unroll
    for (int s = 0; s < SEGS; ++s) { csl[s] = cs[s]; over |= (csl[s] > SEGCAP); }
    if (over) { if (lane == 0) flag[row] = 1; return; }

    const int pos = pos_[row];
    const float ps = ps_[row];
    const uint32_t* cl = cand + (size_t)row * SEGS * SEGCAP;
    const float* rowp = input + (size_t)row * YN;

    // slots: 4 per lane; cache entries for the rank pass
    uint32_t ecache[4]; bool vcache[4];
    uint32_t mk = 0xFFFFFFFFu;
#pragma unroll
    for (int it = 0; it < 4; ++it) {
        int slot = lane + 64 * it;
        int s = slot >> 5, idx = slot & 31;
        bool valid = (uint32_t)idx < csl[s];
        uint32_t e = valid ? cl[slot] : 0xFFFFFFFFu;
        ecache[it] = e; vcache[it] = valid;
        if (valid) {
            int col = (int)(e & 0x1FFFFu);
            if (col != pos) {
                float sc = rowp[col];
                if ((1.0f + sc) - ps >= 0.0f && e < mk) mk = e;
            }
        }
    }
    for (int off = 32; off > 0; off >>= 1) {
        uint32_t o = (uint32_t)__shfl_xor((int)mk, off, 64);
        mk = (o < mk) ? o : mk;
    }
    if (mk == 0xFFFFFFFFu) {           // no violating candidate -> exact fallback
        if (lane == 0) flag[row] = 1;
        return;
    }
    uint32_t c = 0;
#pragma unroll
    for (int it = 0; it < 4; ++it) {
        uint32_t e = ecache[it];
        int col = (int)(e & 0x1FFFFu);
        c += (vcache[it] && (e < mk) && (col != pos)) ? 1u : 0u;
    }
    for (int off = 32; off > 0; off >>= 1) c += (uint32_t)__shfl_xor((int)c, off, 64);
    if (lane == 0) {
        flag[row] = 0;
        uint32_t rank = c;
        float loss = 0.0f;
        if (rank < (uint32_t)mt_ptr[0]) {
            int cstar = (int)(mk & 0x1FFFFu);
            float ns = rowp[cstar];
            float nt = (float)(rank + 1u);
            loss = logf(floorf(49999.0f / nt)) * ((1.0f - ps) + ns);
        }
        row_loss[row] = loss;
    }
}

// ---------------- Kernel 3: exact full-scan fallback (rare rows) ------------
__global__ __launch_bounds__(256) void fallback_kernel(
    const float* __restrict__ input, const int* __restrict__ flag,
    const int* __restrict__ pos_, const float* __restrict__ ps_,
    const int* __restrict__ mt_ptr, float* __restrict__ row_loss)
{
    const int row = blockIdx.x;
    if (!flag[row]) return;
    const int tid = threadIdx.x;
    const int pos = pos_[row];
    const float ps = ps_[row];
    const uint32_t base32 = (uint32_t)row * (uint32_t)YN;
    const float* rowp = input + (size_t)row * YN;

    __shared__ uint64_t smin[256];
    __shared__ uint32_t ssum[256];

    uint64_t mk = ~0ull;
    for (int col = tid; col < YN; col += 256) {
        uint32_t bits = tf_bits(base32 + (uint32_t)col);
        uint64_t key = ((uint64_t)(bits >> 9) << 17) | (uint32_t)col;
        float m = (1.0f + rowp[col]) - ps;
        if ((m >= 0.0f) && (col != pos) && (key < mk)) mk = key;
    }
    smin[tid] = mk;
    __syncthreads();
    for (int s = 128; s > 0; s >>= 1) {
        if (tid < s) { uint64_t o = smin[tid + s]; if (o < smin[tid]) smin[tid] = o; }
        __syncthreads();
    }
    const uint64_t kstar = smin[0];
    if (kstar == ~0ull) {
        if (tid == 0) row_loss[row] = 0.0f;
        return;
    }
    uint32_t c = 0;
    for (int col = tid; col < YN; col += 256) {
        uint32_t bits = tf_bits(base32 + (uint32_t)col);
        uint64_t key = ((uint64_t)(bits >> 9) << 17) | (uint32_t)col;
        c += ((key < kstar) && (col != pos)) ? 1u : 0u;
    }
    ssum[tid] = c;
    __syncthreads();
    for (int s = 128; s > 0; s >>= 1) {
        if (tid < s) ssum[tid] += ssum[tid + s];
        __syncthreads();
    }
    if (tid == 0) {
        uint32_t rank = ssum[0];
        float loss = 0.0f;
        if (rank < (uint32_t)mt_ptr[0]) {
            int cstar = (int)(kstar & 0x1FFFFull);
            float ns = rowp[cstar];
            float nt = (float)(rank + 1u);
            loss = logf(floorf(49999.0f / nt)) * ((1.0f - ps) + ns);
        }
        row_loss[row] = loss;
    }
}

// ---------------- Kernel 4: reduce row losses -> out[0] ---------------------
__global__ __launch_bounds__(256) void reduce_kernel(
    const float* __restrict__ row_loss, float* __restrict__ out)
{
    __shared__ float s[256];
    int tid = threadIdx.x;
    float acc = 0.0f;
    for (int i = tid; i < BN; i += 256) acc += row_loss[i];
    s[tid] = acc;
    __syncthreads();
    for (int st = 128; st > 0; st >>= 1) {
        if (tid < st) s[tid] += s[tid + st];
        __syncthreads();
    }
    if (tid == 0) out[0] = s[0];
}

extern "C" void kernel_launch(void* const* d_in, const int* in_sizes, int n_in,
                              void* d_out, int out_size, void* d_ws, size_t ws_size,
                              hipStream_t stream) {
    const float* input  = (const float*)d_in[0];
    const float* target = (const float*)d_in[1];
    const int*   mt     = (const int*)d_in[2];
    float* out = (float*)d_out;
    WS w = ws_layout(d_ws);

    gen_kernel<<<BN + BN * SEGS, 256, 0, stream>>>(
        input, target, w.cnt_seg, w.cand, w.pos, w.ps);
    resolve_kernel<<<BN / 4, 256, 0, stream>>>(
        input, w.cnt_seg, w.cand, w.pos, w.ps, mt, w.row_loss, w.flag);
    fallback_kernel<<<BN, 256, 0, stream>>>(
        input, w.flag, w.pos, w.ps, mt, w.row_loss);
    reduce_kernel<<<1, 256, 0, stream>>>(w.row_loss, out);
}

// Round 5
// 541.687 us; speedup vs baseline: 1.0120x; 1.0120x over previous
//
#include <hip/hip_runtime.h>
#include <stdint.h>

// WARP loss, B=1024, Y=50000. inputs: input_ f32[B*Y], target f32[B*Y],
// max_num_trials i32[1]; output f32[1] = sum of per-row losses.
//
// Exact-RNG reduction (absmax 0.0 R1-R4): first violator in the random
// permutation == violator with min key (u_bits>>9, col); num_trials-1 ==
// rank == #{cols != pos with key < kstar}. Keys are input-independent:
// gen hashes the flat 51.2M counter domain (zero tail waste), pushing the
// ~50/row keys with bits < 2^22 (keyhi < 2^13) into per-row lists; resolve
// margin-tests candidates only; rare rows fall back to an exact full scan.
#define BN 1024
#define YN 50000
#define NTOT (BN * YN)          // 51,200,000
#define NGROUPS (NTOT / 4)      // 12,800,000 exact
#define CAP 96                  // Poisson(48.8)/row, P(>96) ~ 5e-10
#define BITS_T (1u << 22)       // raw-bits threshold == keyhi < 2^13
#define HASH_BLOCKS 4096
#define STRIDE (HASH_BLOCKS * 256)   // groups advance per iteration

// ---------------- Threefry-2x32, key (0,42), counter (0, i), 4-wide ---------
// ks0 = 0, ks1 = 42, ks2 = 0x1BD11BDA ^ 42 = 0x1BD11BF0
#define ROTL(x, r) __builtin_amdgcn_alignbit((x), (x), 32u - (r))
#define RND(b, a, r) { b += a; a = ROTL(a, r); a ^= b; }
#define RND4(r) { RND(b0,a0,r) RND(b1,a1,r) RND(b2,a2,r) RND(b3,a3,r) }
#define INJ4(db, da) { b0 += (db); b1 += (db); b2 += (db); b3 += (db); \
                       a0 += (da); a1 += (da); a2 += (da); a3 += (da); }

// single-counter variant (fallback kernel only; validated R1)
__device__ __forceinline__ uint32_t tf_bits(uint32_t ctr) {
    const uint32_t ks1 = 42u, ks2 = 0x1BD11BF0u;
    uint32_t x0 = 0u, x1 = ctr + ks1;
#define TFR(r) { x0 += x1; x1 = ROTL(x1, r); x1 ^= x0; }
    TFR(13) TFR(15) TFR(26) TFR(6)
    x0 += ks1; x1 += ks2 + 1u;
    TFR(17) TFR(29) TFR(16) TFR(24)
    x0 += ks2; x1 += 2u;
    TFR(13) TFR(15) TFR(26) TFR(6)
    x1 += ks1 + 3u;
    TFR(17) TFR(29) TFR(16) TFR(24)
    x0 += ks1; x1 += ks2 + 4u;
    TFR(13) TFR(15) TFR(26) TFR(6)
    x0 += ks2; x1 += 5u;
    return x0 ^ x1;
}

// ws layout (4B units): cnt[BN] | pos[BN] | ps[BN] | row_loss[BN] | flag[BN]
//                       | cand[BN*CAP]
struct WS {
    uint32_t* cnt; int* pos; float* ps; float* row_loss; int* flag; uint32_t* cand;
};
static inline WS ws_layout(void* d_ws) {
    uint32_t* p = (uint32_t*)d_ws;
    WS w;
    w.cnt = p; w.pos = (int*)(p + BN); w.ps = (float*)(p + 2 * BN);
    w.row_loss = (float*)(p + 3 * BN); w.flag = (int*)(p + 4 * BN);
    w.cand = p + 5 * BN;
    return w;
}

// ---------------- Kernel 1: candidate gen (threefry) + target scan ----------
// blocks [0, BN): target scan (memory-bound, hides under the hash blocks).
// blocks [BN, BN+HASH_BLOCKS): grid-stride over the flat 4-group domain.
__global__ __launch_bounds__(256, 4) void gen_kernel(
    const float* __restrict__ input, const float* __restrict__ target,
    uint32_t* __restrict__ cnt, uint32_t* __restrict__ cand,
    int* __restrict__ pos_out, float* __restrict__ ps_out)
{
    const int tid = threadIdx.x;
    if (blockIdx.x < BN) {
        const int row = blockIdx.x;
        const size_t base = (size_t)row * YN;
        __shared__ volatile int s_pos;
        if (tid == 0) s_pos = -1;
        __syncthreads();
        const float4* t4 = (const float4*)(target + base);
        for (int j4 = tid; j4 < YN / 4; j4 += 256) {
            if (s_pos >= 0) break;               // benign racy early-exit
            float4 v = t4[j4];
            int c0 = 4 * j4;
            if (v.x != 0.0f) s_pos = c0;
            if (v.y != 0.0f) s_pos = c0 + 1;
            if (v.z != 0.0f) s_pos = c0 + 2;
            if (v.w != 0.0f) s_pos = c0 + 3;
        }
        __syncthreads();
        if (tid == 0) {
            int p = s_pos;
            pos_out[row] = p;
            ps_out[row] = input[base + p];
        }
        return;
    }
    const uint32_t gid = (uint32_t)(blockIdx.x - BN) * 256u + (uint32_t)tid;
    const uint32_t ks1 = 42u, ks2 = 0x1BD11BF0u;
    for (uint32_t g = gid; g < NGROUPS; g += STRIDE) {
        const uint32_t c4 = g << 2;              // first counter of the group
        uint32_t a0 = c4 + 42u, a1 = c4 + 43u, a2 = c4 + 44u, a3 = c4 + 45u;
        uint32_t b0 = 0u, b1 = 0u, b2 = 0u, b3 = 0u;
        RND4(13) RND4(15) RND4(26) RND4(6)
        INJ4(ks1, ks2 + 1u)
        RND4(17) RND4(29) RND4(16) RND4(24)
        INJ4(ks2, 2u)
        RND4(13) RND4(15) RND4(26) RND4(6)
        INJ4(0u, ks1 + 3u)
        RND4(17) RND4(29) RND4(16) RND4(24)
        INJ4(ks1, ks2 + 4u)
        RND4(13) RND4(15) RND4(26) RND4(6)
        INJ4(ks2, 5u)
        const uint32_t o0 = b0 ^ a0, o1 = b1 ^ a1, o2 = b2 ^ a2, o3 = b3 ^ a3;
        const uint32_t m01 = o0 < o1 ? o0 : o1;
        const uint32_t m23 = o2 < o3 ? o2 : o3;
        const uint32_t m = m01 < m23 ? m01 : m23;
        if (__builtin_expect(m < BITS_T, 0)) {   // ~1/256 of groups
            const uint32_t os[4] = {o0, o1, o2, o3};
#pragma unroll
            for (int k = 0; k < 4; ++k) {
                if (os[k] < BITS_T) {
                    const uint32_t idx = c4 + (uint32_t)k;
                    const uint32_t row = idx / 50000u;      // magic-mul
                    const uint32_t col = idx - row * 50000u;
                    const uint32_t slot = atomicAdd(&cnt[row], 1u);
                    if (slot < CAP)
                        cand[row * CAP + slot] = ((os[k] >> 9) << 17) | col;
                }
            }
        }
    }
}

// ---------------- Kernel 2: resolve per row from candidate list -------------
// one wave per row; always writes flag[row] (0 done, 1 -> fallback).
__global__ __launch_bounds__(256) void resolve_kernel(
    const float* __restrict__ input, const uint32_t* __restrict__ cnt,
    const uint32_t* __restrict__ cand, const int* __restrict__ pos_,
    const float* __restrict__ ps_, const int* __restrict__ mt_ptr,
    float* __restrict__ row_loss, int* __restrict__ flag)
{
    const int gtid = blockIdx.x * 256 + threadIdx.x;
    const int row = gtid >> 6;
    const int lane = gtid & 63;
    const uint32_t n = cnt[row];
    if (n > CAP) { if (lane == 0) flag[row] = 1; return; }
    const int pos = pos_[row];
    const float ps = ps_[row];
    const uint32_t* cl = cand + row * CAP;
    const float* rowp = input + (size_t)row * YN;

    uint32_t e0 = 0xFFFFFFFFu, e1 = 0xFFFFFFFFu;    // <=2 entries/lane (CAP=96)
    if ((uint32_t)lane < n) e0 = cl[lane];
    if ((uint32_t)(lane + 64) < n) e1 = cl[lane + 64];

    uint32_t mk = 0xFFFFFFFFu;
    {
        int col = (int)(e0 & 0x1FFFFu);
        if (e0 != 0xFFFFFFFFu && col != pos &&
            (1.0f + rowp[col]) - ps >= 0.0f) mk = e0;
        col = (int)(e1 & 0x1FFFFu);
        if (e1 != 0xFFFFFFFFu && col != pos &&
            (1.0f + rowp[col]) - ps >= 0.0f && e1 < mk) mk = e1;
    }
    for (int off = 32; off > 0; off >>= 1) {
        uint32_t o = (uint32_t)__shfl_xor((int)mk, off, 64);
        mk = (o < mk) ? o : mk;
    }
    if (mk == 0xFFFFFFFFu) {            // no violating candidate -> exact fallback
        if (lane == 0) flag[row] = 1;
        return;
    }
    uint32_t c = 0;
    c += (e0 < mk && (int)(e0 & 0x1FFFFu) != pos) ? 1u : 0u;
    c += (e1 < mk && (int)(e1 & 0x1FFFFu) != pos) ? 1u : 0u;
    for (int off = 32; off > 0; off >>= 1) c += (uint32_t)__shfl_xor((int)c, off, 64);
    if (lane == 0) {
        flag[row] = 0;
        float loss = 0.0f;
        if (c < (uint32_t)mt_ptr[0]) {
            int cstar = (int)(mk & 0x1FFFFu);
            float ns = rowp[cstar];
            float nt = (float)(c + 1u);
            loss = logf(floorf(49999.0f / nt)) * ((1.0f - ps) + ns);
        }
        row_loss[row] = loss;
    }
}

// ---------------- Kernel 3: exact full-scan fallback (rare rows) ------------
__global__ __launch_bounds__(256) void fallback_kernel(
    const float* __restrict__ input, const int* __restrict__ flag,
    const int* __restrict__ pos_, const float* __restrict__ ps_,
    const int* __restrict__ mt_ptr, float* __restrict__ row_loss)
{
    const int row = blockIdx.x;
    if (!flag[row]) return;
    const int tid = threadIdx.x;
    const int pos = pos_[row];
    const float ps = ps_[row];
    const uint32_t base32 = (uint32_t)row * (uint32_t)YN;
    const float* rowp = input + (size_t)row * YN;

    __shared__ uint64_t smin[256];
    __shared__ uint32_t ssum[256];

    uint64_t mk = ~0ull;
    for (int col = tid; col < YN; col += 256) {
        uint32_t bits = tf_bits(base32 + (uint32_t)col);
        uint64_t key = ((uint64_t)(bits >> 9) << 17) | (uint32_t)col;
        float mrg = (1.0f + rowp[col]) - ps;
        if ((mrg >= 0.0f) && (col != pos) && (key < mk)) mk = key;
    }
    smin[tid] = mk;
    __syncthreads();
    for (int s = 128; s > 0; s >>= 1) {
        if (tid < s) { uint64_t o = smin[tid + s]; if (o < smin[tid]) smin[tid] = o; }
        __syncthreads();
    }
    const uint64_t kstar = smin[0];
    if (kstar == ~0ull) {
        if (tid == 0) row_loss[row] = 0.0f;
        return;
    }
    uint32_t c = 0;
    for (int col = tid; col < YN; col += 256) {
        uint32_t bits = tf_bits(base32 + (uint32_t)col);
        uint64_t key = ((uint64_t)(bits >> 9) << 17) | (uint32_t)col;
        c += ((key < kstar) && (col != pos)) ? 1u : 0u;
    }
    ssum[tid] = c;
    __syncthreads();
    for (int s = 128; s > 0; s >>= 1) {
        if (tid < s) ssum[tid] += ssum[tid + s];
        __syncthreads();
    }
    if (tid == 0) {
        uint32_t rank = ssum[0];
        float loss = 0.0f;
        if (rank < (uint32_t)mt_ptr[0]) {
            int cstar = (int)(kstar & 0x1FFFFull);
            float ns = rowp[cstar];
            float nt = (float)(rank + 1u);
            loss = logf(floorf(49999.0f / nt)) * ((1.0f - ps) + ns);
        }
        row_loss[row] = loss;
    }
}

// ---------------- Kernel 4: reduce row losses -> out[0] ---------------------
__global__ __launch_bounds__(256) void reduce_kernel(
    const float* __restrict__ row_loss, float* __restrict__ out)
{
    __shared__ float s[256];
    int tid = threadIdx.x;
    float acc = 0.0f;
    for (int i = tid; i < BN; i += 256) acc += row_loss[i];
    s[tid] = acc;
    __syncthreads();
    for (int st = 128; st > 0; st >>= 1) {
        if (tid < st) s[tid] += s[tid + st];
        __syncthreads();
    }
    if (tid == 0) out[0] = s[0];
}

extern "C" void kernel_launch(void* const* d_in, const int* in_sizes, int n_in,
                              void* d_out, int out_size, void* d_ws, size_t ws_size,
                              hipStream_t stream) {
    const float* input  = (const float*)d_in[0];
    const float* target = (const float*)d_in[1];
    const int*   mt     = (const int*)d_in[2];
    float* out = (float*)d_out;
    WS w = ws_layout(d_ws);

    hipMemsetAsync(w.cnt, 0, BN * sizeof(uint32_t), stream);   // 4 KB
    gen_kernel<<<BN + HASH_BLOCKS, 256, 0, stream>>>(
        input, target, w.cnt, w.cand, w.pos, w.ps);
    resolve_kernel<<<BN / 4, 256, 0, stream>>>(
        input, w.cnt, w.cand, w.pos, w.ps, mt, w.row_loss, w.flag);
    fallback_kernel<<<BN, 256, 0, stream>>>(
        input, w.flag, w.pos, w.ps, mt, w.row_loss);
    reduce_kernel<<<1, 256, 0, stream>>>(w.row_loss, out);
}

// Round 6
// 536.490 us; speedup vs baseline: 1.0218x; 1.0097x over previous
//
#include <hip/hip_runtime.h>
#include <stdint.h>

// WARP loss, B=1024, Y=50000. inputs: input_ f32[B*Y], target f32[B*Y],
// max_num_trials i32[1]; output f32[1] = sum of per-row losses.
//
// Exact-RNG reduction (absmax 0.0 R1-R5): first violator in the random
// permutation == violator with min key (u_bits>>9, col); num_trials-1 ==
// rank == #{cols != pos with key < kstar}. Keys are input-independent:
// gen hashes the flat 51.2M counter domain, pushing keys with bits < 2^22
// (~49/row) into per-row lists; resolve margin-tests candidates only; rows
// with overflow / no violating candidate use an exact full-scan fallback.
// R6: 8 interleaved threefry chains/thread (dep-latency coverage), exact
// domain coverage (no grid-stride checks), per-8 min tree, resolve+fallback
// merged into one kernel.
#define BN 1024
#define YN 50000
#define CAP 96                  // Poisson(48.8)/row, P(>96) ~ 5e-10
#define BITS_T (1u << 22)       // raw-bits threshold == keyhi < 2^13
#define SCANB BN                // target-scan blocks
#define HASHB 5000              // hash blocks: 5000*256*5*8 = 51.2e6 exact
#define ITERS 5

// ---------------- Threefry-2x32, key (0,42), counter (0, i), 8-wide ---------
// ks0 = 0, ks1 = 42, ks2 = 0x1BD11BDA ^ 42 = 0x1BD11BF0
#define ROTL(x, r) __builtin_amdgcn_alignbit((x), (x), 32u - (r))
#define RND(b, a, r) { b += a; a = ROTL(a, r); a ^= b; }
#define R8(r) { RND(b0,a0,r) RND(b1,a1,r) RND(b2,a2,r) RND(b3,a3,r) \
                RND(b4,a4,r) RND(b5,a5,r) RND(b6,a6,r) RND(b7,a7,r) }
#define IB8(db) { b0 += (db); b1 += (db); b2 += (db); b3 += (db); \
                  b4 += (db); b5 += (db); b6 += (db); b7 += (db); }
#define IA8(da) { a0 += (da); a1 += (da); a2 += (da); a3 += (da); \
                  a4 += (da); a5 += (da); a6 += (da); a7 += (da); }

// single-counter variant (fallback path only; validated R1)
__device__ __forceinline__ uint32_t tf_bits(uint32_t ctr) {
    const uint32_t ks1 = 42u, ks2 = 0x1BD11BF0u;
    uint32_t x0 = 0u, x1 = ctr + ks1;
#define TFR(r) { x0 += x1; x1 = ROTL(x1, r); x1 ^= x0; }
    TFR(13) TFR(15) TFR(26) TFR(6)
    x0 += ks1; x1 += ks2 + 1u;
    TFR(17) TFR(29) TFR(16) TFR(24)
    x0 += ks2; x1 += 2u;
    TFR(13) TFR(15) TFR(26) TFR(6)
    x1 += ks1 + 3u;
    TFR(17) TFR(29) TFR(16) TFR(24)
    x0 += ks1; x1 += ks2 + 4u;
    TFR(13) TFR(15) TFR(26) TFR(6)
    x0 += ks2; x1 += 5u;
    return x0 ^ x1;
}

// ws layout (4B units): cnt[BN] | pos[BN] | ps[BN] | row_loss[BN] | cand[BN*CAP]
struct WS { uint32_t* cnt; int* pos; float* ps; float* row_loss; uint32_t* cand; };
static inline WS ws_layout(void* d_ws) {
    uint32_t* p = (uint32_t*)d_ws;
    WS w;
    w.cnt = p; w.pos = (int*)(p + BN); w.ps = (float*)(p + 2 * BN);
    w.row_loss = (float*)(p + 3 * BN); w.cand = p + 4 * BN;
    return w;
}

// ---------------- Kernel 1: candidate gen (threefry) + target scan ----------
// blocks [0, SCANB): target scan (memory-bound, hides under hash blocks).
// blocks [SCANB, SCANB+HASHB): 8 chains/thread, 5 iters, exact coverage.
__global__ __launch_bounds__(256) void gen_kernel(
    const float* __restrict__ input, const float* __restrict__ target,
    uint32_t* __restrict__ cnt, uint32_t* __restrict__ cand,
    int* __restrict__ pos_out, float* __restrict__ ps_out)
{
    const int tid = threadIdx.x;
    if (blockIdx.x < SCANB) {
        const int row = blockIdx.x;
        const size_t base = (size_t)row * YN;
        __shared__ volatile int s_pos;
        if (tid == 0) s_pos = -1;
        __syncthreads();
        const float4* t4 = (const float4*)(target + base);
        for (int j4 = tid; j4 < YN / 4; j4 += 256) {
            if (s_pos >= 0) break;               // benign racy early-exit
            float4 v = t4[j4];
            int c0 = 4 * j4;
            if (v.x != 0.0f) s_pos = c0;
            if (v.y != 0.0f) s_pos = c0 + 1;
            if (v.z != 0.0f) s_pos = c0 + 2;
            if (v.w != 0.0f) s_pos = c0 + 3;
        }
        __syncthreads();
        if (tid == 0) {
            int p = s_pos;
            pos_out[row] = p;
            ps_out[row] = input[base + p];
        }
        return;
    }
    const uint32_t hb = (uint32_t)(blockIdx.x - SCANB);
    const uint32_t ks1 = 42u, ks2 = 0x1BD11BF0u;
#pragma unroll 1
    for (uint32_t it = 0; it < ITERS; ++it) {
        const uint32_t chunk = (it * HASHB + hb) * 256u + (uint32_t)tid;
        const uint32_t c8 = chunk * 8u;
        uint32_t a0 = c8 + 42u, a1 = c8 + 43u, a2 = c8 + 44u, a3 = c8 + 45u;
        uint32_t a4 = c8 + 46u, a5 = c8 + 47u, a6 = c8 + 48u, a7 = c8 + 49u;
        uint32_t b0 = 0u, b1 = 0u, b2 = 0u, b3 = 0u;
        uint32_t b4 = 0u, b5 = 0u, b6 = 0u, b7 = 0u;
        R8(13) R8(15) R8(26) R8(6)
        IB8(ks1) IA8(ks2 + 1u)
        R8(17) R8(29) R8(16) R8(24)
        IB8(ks2) IA8(2u)
        R8(13) R8(15) R8(26) R8(6)
        IA8(ks1 + 3u)                            // db = ks0 = 0 folded
        R8(17) R8(29) R8(16) R8(24)
        IB8(ks1) IA8(ks2 + 4u)
        R8(13) R8(15) R8(26) R8(6)
        IB8(ks2) IA8(5u)
        const uint32_t o0 = b0 ^ a0, o1 = b1 ^ a1, o2 = b2 ^ a2, o3 = b3 ^ a3;
        const uint32_t o4 = b4 ^ a4, o5 = b5 ^ a5, o6 = b6 ^ a6, o7 = b7 ^ a7;
        uint32_t m01 = o0 < o1 ? o0 : o1,  m23 = o2 < o3 ? o2 : o3;
        uint32_t m45 = o4 < o5 ? o4 : o5,  m67 = o6 < o7 ? o6 : o7;
        uint32_t mA = m01 < m23 ? m01 : m23, mB = m45 < m67 ? m45 : m67;
        if (__builtin_expect((mA < mB ? mA : mB) < BITS_T, 0)) {  // ~1/128
            const uint32_t os[8] = {o0, o1, o2, o3, o4, o5, o6, o7};
#pragma unroll
            for (int k = 0; k < 8; ++k) {
                if (os[k] < BITS_T) {
                    const uint32_t idx = c8 + (uint32_t)k;
                    const uint32_t row = idx / 50000u;      // magic-mul
                    const uint32_t col = idx - row * 50000u;
                    const uint32_t slot = atomicAdd(&cnt[row], 1u);
                    if (slot < CAP)
                        cand[row * CAP + slot] = ((os[k] >> 9) << 17) | col;
                }
            }
        }
    }
}

// ---------------- Kernel 2: resolve (fast path) + exact fallback, fused -----
// one block (256 thr) per row.
__global__ __launch_bounds__(256) void resolve_fb_kernel(
    const float* __restrict__ input, const uint32_t* __restrict__ cnt,
    const uint32_t* __restrict__ cand, const int* __restrict__ pos_,
    const float* __restrict__ ps_, const int* __restrict__ mt_ptr,
    float* __restrict__ row_loss)
{
    const int row = blockIdx.x;
    const int tid = threadIdx.x;
    const uint32_t n = cnt[row];
    const int pos = pos_[row];
    const float ps = ps_[row];
    const float* rowp = input + (size_t)row * YN;
    const uint32_t maxt = (uint32_t)mt_ptr[0];

    __shared__ uint32_t s32[256];
    bool need_fallback = (n > CAP);

    if (!need_fallback) {
        // fast path on candidate list (all keys < T are present)
        const uint32_t* cl = cand + row * CAP;
        uint32_t e = 0xFFFFFFFFu;
        int ecol = -1;
        if ((uint32_t)tid < n) { e = cl[tid]; ecol = (int)(e & 0x1FFFFu); }
        uint32_t mk = 0xFFFFFFFFu;
        if (ecol >= 0 && ecol != pos && (1.0f + rowp[ecol]) - ps >= 0.0f) mk = e;
        s32[tid] = mk;
        __syncthreads();
        for (int s = 128; s > 0; s >>= 1) {
            if (tid < s) { uint32_t o = s32[tid + s]; if (o < s32[tid]) s32[tid] = o; }
            __syncthreads();
        }
        mk = s32[0];
        __syncthreads();
        if (mk != 0xFFFFFFFFu) {
            uint32_t c = (e < mk && ecol != pos) ? 1u : 0u;
            s32[tid] = c;
            __syncthreads();
            for (int s = 128; s > 0; s >>= 1) {
                if (tid < s) s32[tid] += s32[tid + s];
                __syncthreads();
            }
            if (tid == 0) {
                uint32_t rank = s32[0];
                float loss = 0.0f;
                if (rank < maxt) {
                    int cstar = (int)(mk & 0x1FFFFu);
                    float ns = rowp[cstar];
                    float nt = (float)(rank + 1u);
                    loss = logf(floorf(49999.0f / nt)) * ((1.0f - ps) + ns);
                }
                row_loss[row] = loss;
            }
            return;
        }
        need_fallback = true;   // no violating candidate -> exact full scan
    }

    // ---- exact full-scan fallback (rare; validated R1 logic) ----
    __shared__ uint64_t s64[256];
    const uint32_t base32 = (uint32_t)row * (uint32_t)YN;
    uint64_t mk = ~0ull;
    for (int col = tid; col < YN; col += 256) {
        uint32_t bits = tf_bits(base32 + (uint32_t)col);
        uint64_t key = ((uint64_t)(bits >> 9) << 17) | (uint32_t)col;
        float mrg = (1.0f + rowp[col]) - ps;
        if ((mrg >= 0.0f) && (col != pos) && (key < mk)) mk = key;
    }
    s64[tid] = mk;
    __syncthreads();
    for (int s = 128; s > 0; s >>= 1) {
        if (tid < s) { uint64_t o = s64[tid + s]; if (o < s64[tid]) s64[tid] = o; }
        __syncthreads();
    }
    const uint64_t kstar = s64[0];
    if (kstar == ~0ull) {
        if (tid == 0) row_loss[row] = 0.0f;
        return;
    }
    uint32_t c = 0;
    for (int col = tid; col < YN; col += 256) {
        uint32_t bits = tf_bits(base32 + (uint32_t)col);
        uint64_t key = ((uint64_t)(bits >> 9) << 17) | (uint32_t)col;
        c += ((key < kstar) && (col != pos)) ? 1u : 0u;
    }
    s32[tid] = c;
    __syncthreads();
    for (int s = 128; s > 0; s >>= 1) {
        if (tid < s) s32[tid] += s32[tid + s];
        __syncthreads();
    }
    if (tid == 0) {
        uint32_t rank = s32[0];
        float loss = 0.0f;
        if (rank < maxt) {
            int cstar = (int)(kstar & 0x1FFFFull);
            float ns = rowp[cstar];
            float nt = (float)(rank + 1u);
            loss = logf(floorf(49999.0f / nt)) * ((1.0f - ps) + ns);
        }
        row_loss[row] = loss;
    }
}

// ---------------- Kernel 3: reduce row losses -> out[0] ---------------------
__global__ __launch_bounds__(256) void reduce_kernel(
    const float* __restrict__ row_loss, float* __restrict__ out)
{
    __shared__ float s[256];
    int tid = threadIdx.x;
    float acc = 0.0f;
    for (int i = tid; i < BN; i += 256) acc += row_loss[i];
    s[tid] = acc;
    __syncthreads();
    for (int st = 128; st > 0; st >>= 1) {
        if (tid < st) s[tid] += s[tid + st];
        __syncthreads();
    }
    if (tid == 0) out[0] = s[0];
}

extern "C" void kernel_launch(void* const* d_in, const int* in_sizes, int n_in,
                              void* d_out, int out_size, void* d_ws, size_t ws_size,
                              hipStream_t stream) {
    const float* input  = (const float*)d_in[0];
    const float* target = (const float*)d_in[1];
    const int*   mt     = (const int*)d_in[2];
    float* out = (float*)d_out;
    WS w = ws_layout(d_ws);

    hipMemsetAsync(w.cnt, 0, BN * sizeof(uint32_t), stream);   // 4 KB
    gen_kernel<<<SCANB + HASHB, 256, 0, stream>>>(
        input, target, w.cnt, w.cand, w.pos, w.ps);
    resolve_fb_kernel<<<BN, 256, 0, stream>>>(
        input, w.cnt, w.cand, w.pos, w.ps, mt, w.row_loss);
    reduce_kernel<<<1, 256, 0, stream>>>(w.row_loss, out);
}